// Round 1
// baseline (624.295 us; speedup 1.0000x reference)
//
#include <hip/hip_runtime.h>
#include <hip/hip_bf16.h>
#include <stdint.h>

// ---------------------------------------------------------------------------
// CharToWord: bidirectional char-GRU + attention pooling, MFMA bf16 pipeline.
//   prep_kernel : xp[char][gates] tables (input proj is a table lookup!),
//                 Whh / Wp converted to bf16 MFMA fragment-linear layout.
//   gru_kernel  : 64 words/block, 20 steps, G = h @ Whh^T via 16x16x32 bf16
//                 MFMA (Whh in LDS), gates on VALU, h kept f32 in regs.
//                 Writes h-sequence (masked: zeros beyond len) to ws (bf16).
//   attn_kernel : per 64 words, per t: stage Out_t, proj-MFMA vs Wp (from L2),
//                 scores -> online softmax accumulation -> final [B,256] f32.
// ---------------------------------------------------------------------------

typedef unsigned short u16;
typedef float f32x4 __attribute__((ext_vector_type(4)));
typedef __bf16 bf16x8 __attribute__((ext_vector_type(8)));

#if __has_builtin(__builtin_amdgcn_exp2f)
#define EXP2F(x) __builtin_amdgcn_exp2f(x)
#else
#define EXP2F(x) exp2f(x)
#endif
#if __has_builtin(__builtin_amdgcn_rcpf)
#define RCPF(x) __builtin_amdgcn_rcpf(x)
#else
#define RCPF(x) (1.0f / (x))
#endif

#define LOG2E 1.4426950408889634f

__device__ __forceinline__ u16 f2b(float f) {
  uint32_t u = __builtin_bit_cast(uint32_t, f);
  u = u + 0x7FFFu + ((u >> 16) & 1u);
  return (u16)(u >> 16);
}
__device__ __forceinline__ float b2f(u16 s) {
  uint32_t u = ((uint32_t)s) << 16;
  return __builtin_bit_cast(float, u);
}
__device__ __forceinline__ float fast_sig(float x) {
  return RCPF(1.0f + EXP2F(-LOG2E * x));
}
__device__ __forceinline__ float fast_tanh(float x) {
  return 1.0f - 2.0f * RCPF(EXP2F(2.0f * LOG2E * x) + 1.0f);
}

// ---------------------------------------------------------------------------
// prep: grid 576 x 256
//  blocks [0,512)   : xp2 tables, layout [c][wv*16+col][8] (idx = cls*2+j2)
//  blocks [512,560) : Whh frag bf16, chunks ((nt*4+kt)*64+lane)*8
//  blocks [560,576) : Wp frag bf16,  chunks ((nt*8+kt)*64+lane)*8
// ---------------------------------------------------------------------------
__global__ void prep_kernel(
    const float* __restrict__ emb,
    const float* __restrict__ wih_f, const float* __restrict__ bih_f,
    const float* __restrict__ wih_b, const float* __restrict__ bih_b,
    const float* __restrict__ whh_f_in, const float* __restrict__ whh_b_in,
    const float* __restrict__ wp_in,
    float* __restrict__ xp2_f, float* __restrict__ xp2_b,
    u16* __restrict__ whhf, u16* __restrict__ whhb, u16* __restrict__ wpf) {
  int gid = blockIdx.x * 256 + threadIdx.x;
  if (blockIdx.x < 512) {
    int d = gid >> 16;          // 65536 entries per direction
    int r = gid & 65535;
    int c = r >> 9;             // 512 per char
    int r2 = r & 511;
    int wc = r2 >> 3;           // wv*16 + col
    int i8 = r2 & 7;
    float v = 0.f;
    if (i8 < 6) {
      int cls = i8 >> 1, j2 = i8 & 1;
      int gate = cls * 128 + (wc >> 4) * 32 + j2 * 16 + (wc & 15);
      const float* wih = d ? wih_b : wih_f;
      const float* bih = d ? bih_b : bih_f;
      float s = 0.f;
      for (int e = 0; e < 64; e++) s += emb[c * 64 + e] * wih[gate * 64 + e];
      v = s + bih[gate];
    }
    (d ? xp2_b : xp2_f)[(c << 9) + r2] = v;
  } else if (blockIdx.x < 560) {
    int idx = gid - 512 * 256;  // 0..12287
    int d = (idx >= 6144) ? 1 : 0;
    int r = idx - d * 6144;
    int lane = r & 63, kt = (r >> 6) & 3, nt = r >> 8;
    int n = nt * 16 + (lane & 15);
    int k0 = kt * 32 + (lane >> 4) * 8;
    const float* w = d ? whh_b_in : whh_f_in;
    u16* o = (d ? whhb : whhf) + r * 8;
    for (int j = 0; j < 8; j++) o[j] = f2b(w[n * 128 + k0 + j]);
  } else {
    int idx = gid - 560 * 256;  // 0..4095
    if (idx < 4096) {
      int lane = idx & 63, kt = (idx >> 6) & 7, nt = idx >> 9;
      int n = nt * 16 + (lane & 15);
      int k0 = kt * 32 + (lane >> 4) * 8;
      u16* o = wpf + idx * 8;
      for (int j = 0; j < 8; j++) o[j] = f2b(wp_in[n * 256 + k0 + j]);
    }
  }
}

// ---------------------------------------------------------------------------
// gru: grid 2*cb x 256. blockIdx parity = direction. 64 words per block.
// Wave wv owns gate triples hid in [wv*32, wv*32+32): n_tiles cls*8 + wv*2 + j2.
// ---------------------------------------------------------------------------
__global__ __launch_bounds__(256, 1) void gru_kernel(
    const int* __restrict__ chars, const int* __restrict__ lens,
    const float* __restrict__ xp2_f, const float* __restrict__ xp2_b,
    const u16* __restrict__ whhf, const u16* __restrict__ whhb,
    const float* __restrict__ bhh_f, const float* __restrict__ bhh_b,
    u16* __restrict__ hf, u16* __restrict__ hb, int word_off) {
  const int dir = blockIdx.x & 1;
  const int blk = blockIdx.x >> 1;
  const int gw0 = word_off + blk * 64;
  const float* xp2 = dir ? xp2_b : xp2_f;
  const u16* whh = dir ? whhb : whhf;
  const float* bhh = dir ? bhh_b : bhh_f;
  u16* hout = (dir ? hb : hf) + (size_t)blk * 64 * 20 * 128;

  __shared__ u16 whh_s[49152];          // 96 KiB: Whh frags
  __shared__ u16 h_s[8192];             // 16 KiB: h in A-frag layout
  __shared__ unsigned char chars_s[20 * 64];
  __shared__ unsigned char lens_s[64];

  const int tid = threadIdx.x;
  {
    const uint4* src = (const uint4*)whh;
    uint4* dst = (uint4*)whh_s;
#pragma unroll
    for (int i = 0; i < 24; i++) dst[tid + i * 256] = src[tid + i * 256];
  }
  for (int i = tid; i < 1280; i += 256) {
    int w = i & 63, t = i >> 6;
    chars_s[t * 64 + w] = (unsigned char)chars[(gw0 + w) * 20 + t];
  }
  if (tid < 64) lens_s[tid] = (unsigned char)lens[gw0 + tid];
  {
    uint32_t* hz = (uint32_t*)h_s;
    for (int i = tid; i < 4096; i += 256) hz[i] = 0u;
  }
  __syncthreads();

  const int wv = tid >> 6;
  const int ln = tid & 63;
  const int col = ln & 15;
  const int grp = ln >> 4;

  float bh[6];
#pragma unroll
  for (int n = 0; n < 6; n++) {
    int cls = n >> 1, j2 = n & 1;
    bh[n] = bhh[cls * 128 + wv * 32 + j2 * 16 + col];
  }

  int Lw[4][4];
#pragma unroll
  for (int m = 0; m < 4; m++)
#pragma unroll
    for (int r = 0; r < 4; r++) Lw[m][r] = lens_s[m * 16 + grp * 4 + r];

  const int cw = tid & 15;  // copy-phase word-within-tile
  int Lc[4];
#pragma unroll
  for (int g = 0; g < 4; g++) Lc[g] = lens_s[g * 16 + cw];

  float h[4][4][2];
#pragma unroll
  for (int m = 0; m < 4; m++)
#pragma unroll
    for (int r = 0; r < 4; r++) {
      h[m][r][0] = 0.f;
      h[m][r][1] = 0.f;
    }

  for (int s = 0; s < 20; s++) {
    // ---- xp prefetch (from L2-resident table) ----
    float xpv[4][4][6];
#pragma unroll
    for (int m = 0; m < 4; m++) {
#pragma unroll
      for (int r = 0; r < 4; r++) {
        int w = m * 16 + grp * 4 + r;
        int L = Lw[m][r];
        int t = dir ? ((s < L) ? (L - 1 - s) : s) : s;
        int c = chars_s[t * 64 + w];
        const float* base = xp2 + (((c * 64) + wv * 16 + col) << 3);
        float4 a = *(const float4*)base;
        float2 b = *(const float2*)(base + 4);
        xpv[m][r][0] = a.x; xpv[m][r][1] = a.y;
        xpv[m][r][2] = a.z; xpv[m][r][3] = a.w;
        xpv[m][r][4] = b.x; xpv[m][r][5] = b.y;
      }
    }

    // ---- hp = h @ Whh^T + bhh via MFMA ----
    f32x4 acc[6][4];
#pragma unroll
    for (int n = 0; n < 6; n++)
#pragma unroll
      for (int m = 0; m < 4; m++) acc[n][m] = (f32x4){bh[n], bh[n], bh[n], bh[n]};

#pragma unroll
    for (int kt = 0; kt < 4; kt++) {
      bf16x8 Af[4];
#pragma unroll
      for (int m = 0; m < 4; m++)
        Af[m] = *(const bf16x8*)(h_s + (((m * 4 + kt) * 64 + ln) << 3));
#pragma unroll
      for (int n = 0; n < 6; n++) {
        int cls = n >> 1, j2 = n & 1;
        int nt = cls * 8 + wv * 2 + j2;
        bf16x8 Bf = *(const bf16x8*)(whh_s + (((nt * 4 + kt) * 64 + ln) << 3));
#pragma unroll
        for (int m = 0; m < 4; m++)
          acc[n][m] = __builtin_amdgcn_mfma_f32_16x16x32_bf16(Af[m], Bf, acc[n][m], 0, 0, 0);
      }
    }

    __syncthreads();  // everyone done reading h_s

    // ---- gates + h update + write h_s (A-frag layout, bf16) ----
#pragma unroll
    for (int m = 0; m < 4; m++) {
#pragma unroll
      for (int r = 0; r < 4; r++) {
#pragma unroll
        for (int j2 = 0; j2 < 2; j2++) {
          float rr = fast_sig(xpv[m][r][j2] + acc[j2][m][r]);
          float zz = fast_sig(xpv[m][r][2 + j2] + acc[2 + j2][m][r]);
          float nn = fast_tanh(xpv[m][r][4 + j2] + rr * acc[4 + j2][m][r]);
          float hn = (1.f - zz) * nn + zz * h[m][r][j2];
          h[m][r][j2] = hn;
          int hid3 = j2 * 2 + (col >> 3);  // (hid>>3)&3
          int lane_a = (grp * 4 + r) | (hid3 << 4);
          h_s[(((m * 4 + wv) * 64 + lane_a) << 3) + (col & 7)] = f2b(hn);
        }
      }
    }
    __syncthreads();  // h_s complete

    // ---- bulk copy h_s -> global (masked; backward remaps t) ----
    {
      const int k = wv * 32 + grp * 8;
#pragma unroll
      for (int g = 0; g < 4; g++) {
        int w = g * 16 + cw;
        int L = Lc[g];
        int tdst = dir ? ((s < L) ? (L - 1 - s) : s) : s;
        uint4 v;
        if (s >= L) {
          v = make_uint4(0u, 0u, 0u, 0u);
        } else {
          v = *(const uint4*)(h_s + (((g * 4 + wv) * 64 + ln) << 3));
        }
        *(uint4*)(hout + ((size_t)w * 20 + tdst) * 128 + k) = v;
      }
    }
  }
}

// ---------------------------------------------------------------------------
// attn: grid cb x 256. 64 words/block. Online softmax, single read pass.
// ---------------------------------------------------------------------------
__global__ __launch_bounds__(256) void attn_kernel(
    const u16* __restrict__ hf, const u16* __restrict__ hb,
    const u16* __restrict__ wpf,
    const float* __restrict__ bp, const float* __restrict__ ctx,
    float* __restrict__ out, int word_off) {
  const int blk = blockIdx.x;
  const int lw0 = blk * 64;

  __shared__ u16 ot_s[16384];      // 32 KiB: Out_t frag layout
  __shared__ float part_s[4][64];  // per-wave score partials

  const int tid = threadIdx.x;
  const int wv = tid >> 6, ln = tid & 63, col = ln & 15, grp = ln >> 4;
  const int sw = tid >> 2;   // this thread's word (4 threads per word)
  const int seg = tid & 3;   // 64-dim segment of the 256-dim output

  float bpv[2], ctxv[2];
#pragma unroll
  for (int n = 0; n < 2; n++) {
    int nt = wv + n * 4;
    bpv[n] = bp[nt * 16 + col];
    ctxv[n] = ctx[nt * 16 + col];
  }

  float facc[64];
#pragma unroll
  for (int i = 0; i < 64; i++) facc[i] = 0.f;
  float mrun = -3.0e38f, drun = 0.f;

  const u16* srcbase =
      ((seg < 2) ? hf : hb) + (size_t)(lw0 + sw) * 2560 + (seg & 1) * 64;

  for (int t = 0; t < 20; t++) {
    // stage Out_t into frag layout
    {
      const u16* src = srcbase + t * 128;
#pragma unroll
      for (int q = 0; q < 8; q++) {
        uint4 v = *(const uint4*)(src + q * 8);
        int kt = seg * 2 + (q >> 2);
        int lane_a = (sw & 15) | ((q & 3) << 4);
        int m = sw >> 4;
        *(uint4*)(ot_s + (((m * 8 + kt) * 64 + lane_a) << 3)) = v;
      }
    }
    __syncthreads();

    // proj = Out_t @ Wp^T + bp  (Wp frags straight from L2)
    f32x4 acc[2][4];
#pragma unroll
    for (int n = 0; n < 2; n++)
#pragma unroll
      for (int m = 0; m < 4; m++) acc[n][m] = (f32x4){bpv[n], bpv[n], bpv[n], bpv[n]};

#pragma unroll
    for (int kt = 0; kt < 8; kt++) {
      bf16x8 Af[4];
#pragma unroll
      for (int m = 0; m < 4; m++)
        Af[m] = *(const bf16x8*)(ot_s + (((m * 8 + kt) * 64 + ln) << 3));
#pragma unroll
      for (int n = 0; n < 2; n++) {
        int nt = wv + n * 4;
        bf16x8 Bf = *(const bf16x8*)(wpf + (((nt * 8 + kt) * 64 + ln) << 3));
#pragma unroll
        for (int m = 0; m < 4; m++)
          acc[n][m] = __builtin_amdgcn_mfma_f32_16x16x32_bf16(Af[m], Bf, acc[n][m], 0, 0, 0);
      }
    }

    // score partials: sum_c tanh(proj)*ctx, reduce over 16 cols, 4 waves
#pragma unroll
    for (int m = 0; m < 4; m++) {
#pragma unroll
      for (int r = 0; r < 4; r++) {
        float p = fast_tanh(acc[0][m][r]) * ctxv[0] +
                  fast_tanh(acc[1][m][r]) * ctxv[1];
        p += __shfl_xor(p, 1, 64);
        p += __shfl_xor(p, 2, 64);
        p += __shfl_xor(p, 4, 64);
        p += __shfl_xor(p, 8, 64);
        if (col == 0) part_s[wv][m * 16 + grp * 4 + r] = p;
      }
    }
    __syncthreads();

    float sc = part_s[0][sw] + part_s[1][sw] + part_s[2][sw] + part_s[3][sw];

    // online softmax update of (m, d, facc)
    float mnew = fmaxf(mrun, sc);
    float scale = EXP2F(LOG2E * (mrun - mnew));  // 0 on first iter
    float e = EXP2F(LOG2E * (sc - mnew));
    drun = drun * scale + e;
    mrun = mnew;
#pragma unroll
    for (int q = 0; q < 8; q++) {
      int k = seg * 64 + q * 8;
      int kt = k >> 5;
      int lane_a = (sw & 15) | (((k >> 3) & 3) << 4);
      int m = sw >> 4;
      uint4 v = *(const uint4*)(ot_s + (((m * 8 + kt) * 64 + lane_a) << 3));
      const u16* pv = (const u16*)&v;
#pragma unroll
      for (int j = 0; j < 8; j++) facc[q * 8 + j] = facc[q * 8 + j] * scale + e * b2f(pv[j]);
    }
    __syncthreads();  // protect ot_s / part_s reuse
  }

  float inv = RCPF(drun);
  float* dst = out + (size_t)(word_off + lw0 + sw) * 256 + seg * 64;
#pragma unroll
  for (int i = 0; i < 64; i++) dst[i] = facc[i] * inv;
}

// ---------------------------------------------------------------------------
extern "C" void kernel_launch(void* const* d_in, const int* in_sizes, int n_in,
                              void* d_out, int out_size, void* d_ws, size_t ws_size,
                              hipStream_t stream) {
  const int* chars = (const int*)d_in[0];
  const int* lens = (const int*)d_in[1];
  const float* emb = (const float*)d_in[2];
  const float* wih_f = (const float*)d_in[3];
  const float* whh_f = (const float*)d_in[4];
  const float* bih_f = (const float*)d_in[5];
  const float* bhh_f = (const float*)d_in[6];
  const float* wih_b = (const float*)d_in[7];
  const float* whh_b = (const float*)d_in[8];
  const float* bih_b = (const float*)d_in[9];
  const float* bhh_b = (const float*)d_in[10];
  const float* wp = (const float*)d_in[11];
  const float* bp = (const float*)d_in[12];
  const float* ctx = (const float*)d_in[13];
  float* outp = (float*)d_out;

  uint8_t* ws = (uint8_t*)d_ws;
  float* xp2_f = (float*)(ws + 0);            // 512 KiB
  float* xp2_b = (float*)(ws + 524288);       // 512 KiB
  u16* whhf = (u16*)(ws + 1048576);           // 96 KiB
  u16* whhb = (u16*)(ws + 1146880);           // 96 KiB
  u16* wpf = (u16*)(ws + 1245184);            // 64 KiB
  const size_t H_OFF = 1310720;

  prep_kernel<<<576, 256, 0, stream>>>(emb, wih_f, bih_f, wih_b, bih_b, whh_f,
                                       whh_b, wp, xp2_f, xp2_b, whhf, whhb, wpf);

  const size_t per_block = (size_t)64 * 20 * 128 * 2 * 2;  // hf+hb bytes / block
  size_t avail = (ws_size > H_OFF) ? (ws_size - H_OFF) : 0;
  int maxcb = (int)(avail / per_block);
  if (maxcb < 1) maxcb = 1;
  if (maxcb > 512) maxcb = 512;

  for (int done = 0; done < 512;) {
    int cb = (512 - done < maxcb) ? (512 - done) : maxcb;
    u16* hfp = (u16*)(ws + H_OFF);
    u16* hbp = hfp + (size_t)cb * 64 * 20 * 128;
    gru_kernel<<<2 * cb, 256, 0, stream>>>(chars, lens, xp2_f, xp2_b, whhf, whhb,
                                           bhh_f, bhh_b, hfp, hbp, done * 64);
    attn_kernel<<<cb, 256, 0, stream>>>(hfp, hbp, wpf, bp, ctx, outp, done * 64);
    done += cb;
  }
}